// Round 1
// baseline (55.092 us; speedup 1.0000x reference)
//
#include <hip/hip_runtime.h>

// QuantumConv2D closed form:
//   out[b,c,i,j] = cos(theta[9]) * prod_{3x3 window} cos(x[b,c,i+di,j+dj])
//
// Derivation (Heisenberg picture): Z_ancilla conjugated through the RY(theta)
// layer gives cos(t9) Z9 - sin(t9) X9; through the CNOT chain, Z9 -> Z0..Z9
// and X9 is invariant. Product-state expectation: <Z_q> = cos(a_q),
// <X9> = sin(0) = 0. Verified algebraically on the 2-qubit case.

#define BB 16
#define CC 3
#define HH 64
#define WW 64
#define HO 62
#define WO 62

__global__ __launch_bounds__(256) void qconv_closed_form(
    const float* __restrict__ x,      // [B, C, H, W]
    const float* __restrict__ theta,  // [10]
    float* __restrict__ out)          // [B, C, HO, WO]
{
    const int total = BB * CC * HO * WO;
    int idx = blockIdx.x * blockDim.x + threadIdx.x;
    if (idx >= total) return;

    int j  = idx % WO;
    int t  = idx / WO;
    int i  = t % HO;
    int bc = t / HO;  // b*C + c

    const float ct9 = __cosf(theta[9]);  // wave-uniform, scalar-cached

    const float* xp = x + (bc * HH + i) * WW + j;
    float p = ct9;
#pragma unroll
    for (int di = 0; di < 3; ++di) {
        const float* r = xp + di * WW;
        p *= __cosf(r[0]);
        p *= __cosf(r[1]);
        p *= __cosf(r[2]);
    }
    out[idx] = p;
}

extern "C" void kernel_launch(void* const* d_in, const int* in_sizes, int n_in,
                              void* d_out, int out_size, void* d_ws, size_t ws_size,
                              hipStream_t stream) {
    const float* x     = (const float*)d_in[0];
    const float* theta = (const float*)d_in[1];
    float* out         = (float*)d_out;

    const int total = BB * CC * HO * WO;  // 184512 == out_size
    const int block = 256;
    const int grid  = (total + block - 1) / block;
    qconv_closed_form<<<grid, block, 0, stream>>>(x, theta, out);
}

// Round 2
// 54.701 us; speedup vs baseline: 1.0071x; 1.0071x over previous
//
#include <hip/hip_runtime.h>

// QuantumConv2D closed form:
//   out[b,c,i,j] = cos(theta[9]) * prod_{3x3 window} cos(x[b,c,i+di,j+dj])
//
// Heisenberg-picture derivation: Z_ancilla conjugated through the RY(theta)
// layer gives cos(t9) Z9 - sin(t9) X9; through the CNOT chain Z9 -> Z0..Z9,
// X9 invariant. Product-state expectation: <Z_q> = cos(a_q), <X9> = sin(0)=0.
//
// R1: 2x2 output quad per thread over a shared 4x4 input patch —
// 4 loads + 4 cos per output (was 9+9), aligned float2 stores.

#define BB 16
#define CC 3
#define HH 64
#define WW 64
#define HO 62
#define WO 62
#define QD 31            // HO/2 == WO/2
#define NTH (BB * CC * QD * QD)  // 46128 threads

__global__ __launch_bounds__(256) void qconv_quad(
    const float* __restrict__ x,      // [B, C, H, W]
    const float* __restrict__ theta,  // [10]
    float* __restrict__ out)          // [B, C, HO, WO]
{
    int tid = blockIdx.x * blockDim.x + threadIdx.x;
    if (tid >= NTH) return;

    int qj = tid % QD;
    int t  = tid / QD;
    int qi = t % QD;
    int bc = t / QD;     // b*C + c
    int i = qi * 2, j = qj * 2;

    const float ct9 = __cosf(theta[9]);  // wave-uniform

    const float* xp = x + (bc * HH + i) * WW + j;

    // per-row sliding products over cos of 4 consecutive columns
    float p0[4], p1[4];
#pragma unroll
    for (int r = 0; r < 4; ++r) {
        const float* row = xp + r * WW;
        float c0 = __cosf(row[0]);
        float c1 = __cosf(row[1]);
        float c2 = __cosf(row[2]);
        float c3 = __cosf(row[3]);
        float m  = c1 * c2;
        p0[r] = c0 * m;   // cols j..j+2
        p1[r] = m * c3;   // cols j+1..j+3
    }

    float q0 = p0[1] * p0[2] * ct9;
    float q1 = p1[1] * p1[2] * ct9;

    float* op = out + (bc * HO + i) * WO + j;   // i,j even -> 8B aligned
    float2 o0 = make_float2(p0[0] * q0, p1[0] * q1);  // row i
    float2 o1 = make_float2(q0 * p0[3], q1 * p1[3]);  // row i+1
    *(float2*)(op)      = o0;
    *(float2*)(op + WO) = o1;
}

extern "C" void kernel_launch(void* const* d_in, const int* in_sizes, int n_in,
                              void* d_out, int out_size, void* d_ws, size_t ws_size,
                              hipStream_t stream) {
    const float* x     = (const float*)d_in[0];
    const float* theta = (const float*)d_in[1];
    float* out         = (float*)d_out;

    const int block = 256;
    const int grid  = (NTH + block - 1) / block;  // 181 blocks
    qconv_quad<<<grid, block, 0, stream>>>(x, theta, out);
}